// Round 1
// 78.828 us; speedup vs baseline: 1.0095x; 1.0095x over previous
//
#include <hip/hip_runtime.h>
#include <hip/hip_fp16.h>

// ROI pooling: crop_and_resize (bilinear, 14x14) + 2x2 max pool -> (256,7,7,512) fp32
// feature_maps: (2,50,50,512) fp32 NHWC ; rois: (2,128,4) fp32
// reference permutes [1,0,3,2] -> y1=roi[1], x1=roi[0], y2=roi[3], x2=roi[2]
//
// R6: cache-policy + locality pass on top of R5's barrier-free skeleton.
// Theory: tap reads are 200 MB (40x amplification of the 5.12 MB fp16 map);
// rocprof shows our kernels < 46 us each, i.e. ~4.4 TB/s effective read BW ->
// L2 is thrashing. Two causes: (a) consecutive tasks (same ROI) round-robin
// across the 8 XCDs, replicating every ROI's tap set into all eight 4-MiB L2s;
// (b) 25.7 MB of streaming output writes evict fm lines that are re-read ~40x.
// Changes:
//  - XCD-chunked task swizzle: swz=(bid&7)*392+(bid>>3), bijective (3136=8*392).
//    Each XCD owns 32 contiguous ROIs -> small concurrent L2 working set.
//  - __builtin_nontemporal_store for out (write-once); nontemporal loads of the
//    fp32 input in cvt. Keep fmh stores cached (hot data for roi_pool).
//  - Scalarized wave-uniform path: readfirstlane(tid>>6) -> task/ROI decode on
//    SALU, rois via s_load; fewer VALU setup instrs, lower VGPR count.

constexpr int H = 50, W = 50, C = 512;
constexpr int POOLEDX = 7, KSIZE = 2, CROP = 14;
constexpr int RPB = 128;
constexpr int PIX = POOLEDX * POOLEDX;     // 49
constexpr int NROI = 2 * RPB;              // 256
constexpr int NTASK = NROI * PIX;          // 12544 output pixels
constexpr int NELEM = 2 * H * W * C;       // 2,560,000 floats
constexpr int NBLK  = NTASK / 4;           // 3136 blocks
constexpr int NXCD  = 8;
constexpr int CHUNK = NBLK / NXCD;         // 392 (exact)

typedef _Float16 h8 __attribute__((ext_vector_type(8)));
typedef float    f4 __attribute__((ext_vector_type(4)));

// ---------- pre-pass: fm fp32 -> fp16 into workspace ----------
__global__ __launch_bounds__(256) void cvt_kernel(
    const float* __restrict__ in, __half* __restrict__ out)
{
    const int i = (blockIdx.x * 256 + threadIdx.x) * 8;
    const f4* in4 = reinterpret_cast<const f4*>(in + i);
    const f4 a = __builtin_nontemporal_load(in4);      // read-once fp32: don't cache
    const f4 b = __builtin_nontemporal_load(in4 + 1);
    _Float16 h[8];
    h[0] = (_Float16)a[0]; h[1] = (_Float16)a[1];
    h[2] = (_Float16)a[2]; h[3] = (_Float16)a[3];
    h[4] = (_Float16)b[0]; h[5] = (_Float16)b[1];
    h[6] = (_Float16)b[2]; h[7] = (_Float16)b[3];
    // normal (cached) store: fmh is the hot data the main kernel gathers from
    *reinterpret_cast<f4*>(out + i) = *reinterpret_cast<const f4*>(h);
}

// ---------- main: 4 waves/block, one output pixel per wave ----------
__global__ __launch_bounds__(256, 4) void roi_pool_kernel(
    const __half* __restrict__ fmh,
    const float* __restrict__ rois,
    float* __restrict__ out)
{
    // wave-uniform scalar path: readfirstlane makes task SGPR-resident so the
    // ROI decode + rois reads compile to SALU + s_load (constant cache).
    const int wv   = __builtin_amdgcn_readfirstlane((int)(threadIdx.x >> 6));
    const int lane = threadIdx.x & 63;                  // channels 8*lane..

    // XCD-chunked swizzle: blocks are dispatched round-robin across 8 XCDs;
    // give XCD x the contiguous task chunk [x*392*4, (x+1)*392*4).
    const int bid  = blockIdx.x;
    const int swz  = (bid & (NXCD - 1)) * CHUNK + (bid >> 3);
    const int task = swz * 4 + wv;                      // 0..12543

    const int n  = task / PIX;
    const int k  = task - n * PIX;
    const int ph = k / POOLEDX;
    const int pw = k - ph * POOLEDX;
    const int bat = n / RPB;

    const float rx1 = rois[n*4+0], ry1 = rois[n*4+1];
    const float rx2 = rois[n*4+2], ry2 = rois[n*4+3];
    const float ybase = ry1 * (float)(H - 1);
    const float xbase = rx1 * (float)(W - 1);
    const float ystep = ((ry2 - ry1) * (float)(H - 1)) / (float)(CROP - 1);
    const float xstep = ((rx2 - rx1) * (float)(W - 1)) / (float)(CROP - 1);

    // x-tap params (shared across both ky)
    int   x0i[KSIZE], x1i[KSIZE];
    float wx[KSIZE];
    bool  vx[KSIZE];
    #pragma unroll
    for (int kx = 0; kx < KSIZE; ++kx) {
        const float xs = xbase + (float)(pw * KSIZE + kx) * xstep;
        vx[kx] = (xs >= 0.0f) && (xs <= (float)(W - 1));
        const float xf = floorf(xs);
        wx[kx] = xs - xf;
        int xi = (int)xf; xi = min(max(xi, 0), W - 1);
        x0i[kx] = xi;
        x1i[kx] = min(xi + 1, W - 1);
    }

    // base pointer for this wave's 8-channel group
    const __half* base = fmh + (long)bat * (H * W) * C + lane * 8;

    h8 acc;
    #pragma unroll
    for (int c = 0; c < 8; ++c) acc[c] = (_Float16)(-60000.0f);

    #pragma unroll
    for (int ky = 0; ky < KSIZE; ++ky) {
        const float ys = ybase + (float)(ph * KSIZE + ky) * ystep;
        const bool  vy = (ys >= 0.0f) && (ys <= (float)(H - 1));
        const float yf = floorf(ys);
        const float wy = ys - yf;
        int y0 = (int)yf; y0 = min(max(y0, 0), H - 1);
        const int y1 = min(y0 + 1, H - 1);

        #pragma unroll
        for (int kx = 0; kx < KSIZE; ++kx) {
            const h8 t00 = *reinterpret_cast<const h8*>(base + (long)(y0 * W + x0i[kx]) * C);
            const h8 t01 = *reinterpret_cast<const h8*>(base + (long)(y0 * W + x1i[kx]) * C);
            const h8 t10 = *reinterpret_cast<const h8*>(base + (long)(y1 * W + x0i[kx]) * C);
            const h8 t11 = *reinterpret_cast<const h8*>(base + (long)(y1 * W + x1i[kx]) * C);

            // product-form bilinear in packed fp16
            const float wxk = wx[kx];
            const _Float16 w00 = (_Float16)((1.0f - wy) * (1.0f - wxk));
            const _Float16 w01 = (_Float16)((1.0f - wy) * wxk);
            const _Float16 w10 = (_Float16)(wy * (1.0f - wxk));
            const _Float16 w11 = (_Float16)(wy * wxk);

            h8 v = t00 * w00 + t01 * w01 + t10 * w10 + t11 * w11;

            if (!(vx[kx] && vy)) {                      // wave-uniform -> scalar branch
                #pragma unroll
                for (int c = 0; c < 8; ++c) v[c] = (_Float16)0.0f;
            }

#if __has_builtin(__builtin_elementwise_max)
            acc = __builtin_elementwise_max(acc, v);
#else
            #pragma unroll
            for (int c = 0; c < 8; ++c) acc[c] = acc[c] > v[c] ? acc[c] : v[c];
#endif
        }
    }

    // epilogue: fp16 -> fp32, two nontemporal float4 stores (out is write-once;
    // keep it out of L2 so fm tap lines survive)
    f4 o0, o1;
    o0[0] = (float)acc[0]; o0[1] = (float)acc[1]; o0[2] = (float)acc[2]; o0[3] = (float)acc[3];
    o1[0] = (float)acc[4]; o1[1] = (float)acc[5]; o1[2] = (float)acc[6]; o1[3] = (float)acc[7];
    f4* out4 = reinterpret_cast<f4*>(out) + (long)task * (C / 4) + lane * 2;
    __builtin_nontemporal_store(o0, out4);
    __builtin_nontemporal_store(o1, out4 + 1);
}

extern "C" void kernel_launch(void* const* d_in, const int* in_sizes, int n_in,
                              void* d_out, int out_size, void* d_ws, size_t ws_size,
                              hipStream_t stream) {
    const float* fm   = (const float*)d_in[0];
    const float* rois = (const float*)d_in[1];
    float* out  = (float*)d_out;
    __half* fmh = (__half*)d_ws;                       // 5.12 MB << ws_size

    cvt_kernel<<<NELEM / (256 * 8), 256, 0, stream>>>(fm, fmh);     // 1250 blocks
    roi_pool_kernel<<<NBLK, 256, 0, stream>>>(fmh, rois, out);      // 3136 blocks
}